// Round 8
// baseline (79.114 us; speedup 1.0000x reference)
//
#include <hip/hip_runtime.h>
#include <hip/hip_cooperative_groups.h>

namespace cg = cooperative_groups;

#define T_HOR 5
#define MAXIT 100
#define NFLAGS 18
#define EPSC  0.01f

// ===== EXACT R2 body (proven 0.71 us/iter codegen) — do not modify =====
// One LQR sweep for one batch element (two decoupled 2-state subsystems).
// Returns max |du| over all controls/timesteps.
__device__ __forceinline__ float iter_once(
    const float (&c0)[T_HOR], const float (&c1)[T_HOR],
    const float (&gp)[T_HOR], const float (&hp)[T_HOR],
    float xi0, float xi1, float xi2, float xi3,
    float pc_p1, float pc_v1, float pc_p2, float pc_v2,
    float (&ua1)[T_HOR], float (&ub1)[T_HOR],
    float (&ua2)[T_HOR], float (&ub2)[T_HOR])
{
    // rollout
    float xp1[T_HOR], xv1[T_HOR], xp2[T_HOR], xv2[T_HOR];
    xp1[0] = xi0; xp2[0] = xi1; xv1[0] = xi2; xv2[0] = xi3;
    #pragma unroll
    for (int t = 0; t < T_HOR-1; ++t) {
        xp1[t+1] = xp1[t] + 0.1f*xv1[t];
        xv1[t+1] = 0.75f*xv1[t] + 0.5f*(ua1[t]-ub1[t]);
        xp2[t+1] = xp2[t] + 0.1f*xv2[t];
        xv2[t+1] = 0.75f*xv2[t] + 0.5f*(ua2[t]-ub2[t]);
    }

    // backward affine pass
    float ka1[T_HOR], kb1[T_HOR], ka2[T_HOR], kb2[T_HOR];
    float v1p = 0.f, v1v = 0.f, v2p = 0.f, v2v = 0.f;
    #pragma unroll
    for (int t = T_HOR-1; t >= 0; --t) {
        float qa = 0.01f + 0.1f*ua1[t] + 0.5f*v1v;
        float qb = 0.01f + 0.1f*ub1[t] - 0.5f*v1v;
        ka1[t] = -(c0[t]*qa + c1[t]*qb);
        kb1[t] = -(c1[t]*qa + c0[t]*qb);
        float qxp = (pc_p1 + xp1[t]) + v1p;
        float qxv = (pc_v1 + 0.1f*xv1[t]) + 0.1f*v1p + 0.75f*v1v;
        float dq = qa - qb;
        v1p = qxp - gp[t]*dq;
        v1v = qxv - hp[t]*dq;

        float qa2 = 0.01f + 0.1f*ua2[t] + 0.5f*v2v;
        float qb2 = 0.01f + 0.1f*ub2[t] - 0.5f*v2v;
        ka2[t] = -(c0[t]*qa2 + c1[t]*qb2);
        kb2[t] = -(c1[t]*qa2 + c0[t]*qb2);
        float qxp2 = (pc_p2 + xp2[t]) + v2p;
        float qxv2 = (pc_v2 + 0.1f*xv2[t]) + 0.1f*v2p + 0.75f*v2v;
        float dq2 = qa2 - qb2;
        v2p = qxp2 - gp[t]*dq2;
        v2v = qxv2 - hp[t]*dq2;
    }

    // forward pass with clip
    float delta = 0.f;
    float d1p = 0.f, d1v = 0.f, d2p = 0.f, d2v = 0.f;
    #pragma unroll
    for (int t = 0; t < T_HOR; ++t) {
        float phi1 = gp[t]*d1p + hp[t]*d1v;
        float na = fminf(fmaxf(ua1[t] + (ka1[t] - phi1), 0.f), 1.f);
        float nb = fminf(fmaxf(ub1[t] + (kb1[t] + phi1), 0.f), 1.f);
        float dua = na - ua1[t], dub = nb - ub1[t];
        delta = fmaxf(delta, fmaxf(fabsf(dua), fabsf(dub)));
        float n1p = d1p + 0.1f*d1v;
        float n1v = 0.75f*d1v + 0.5f*(dua - dub);
        d1p = n1p; d1v = n1v;
        ua1[t] = na; ub1[t] = nb;

        float phi2 = gp[t]*d2p + hp[t]*d2v;
        float na2 = fminf(fmaxf(ua2[t] + (ka2[t] - phi2), 0.f), 1.f);
        float nb2 = fminf(fmaxf(ub2[t] + (kb2[t] + phi2), 0.f), 1.f);
        float dua2 = na2 - ua2[t], dub2 = nb2 - ub2[t];
        delta = fmaxf(delta, fmaxf(fabsf(dua2), fabsf(dub2)));
        float n2p = d2p + 0.1f*d2v;
        float n2v = 0.75f*d2v + 0.5f*(dua2 - dub2);
        d2p = n2p; d2v = n2v;
        ua2[t] = na2; ub2[t] = nb2;
    }
    return delta;
}

// ===== EXACT R2 kernel structure: ONE uniform group loop, checkpoint+replay.
// Only change vs R2: group length comes from runtime args (g==0 ? g0len : glen)
// instead of compile-time KGRP, so iteration loops can never unroll.
__global__ __launch_bounds__(256)
void mpc_iter_kernel(const float4* __restrict__ x_init,
                     const float4* __restrict__ xd,
                     float4* __restrict__ out,
                     int* __restrict__ gmask,
                     int g0len, int glen)
{
    cg::grid_group grid = cg::this_grid();
    const int b = blockIdx.x * 256 + threadIdx.x;

    const float4 xi  = x_init[b];   // [p1, p2, v1, v2]
    const float4 xdv = xd[b];
    const float SQ01 = 0.31622776601683794f;
    const float pc_p1 = -xdv.x;
    const float pc_p2 = -xdv.y;
    const float pc_v1 = -SQ01 * xdv.z;
    const float pc_v2 = -SQ01 * xdv.w;

    // Batch-independent Riccati gain schedule (constant-folds at compile time)
    float c0[T_HOR], c1[T_HOR], gp[T_HOR], hp[T_HOR];
    {
        float Vpp = 0.f, Vpv = 0.f, Vvv = 0.f;
        #pragma unroll
        for (int t = T_HOR-1; t >= 0; --t) {
            float s  = 0.25f * Vvv;
            float tw = 0.1f + 2.f*s;
            float dd = 0.1f * tw;
            c0[t] = (0.1f + s) / dd;
            c1[t] = s / dd;
            float g = 0.5f * Vpv;
            float h = 0.05f * Vpv + 0.375f * Vvv;
            float inv = 1.f / tw;
            gp[t] = g * inv;
            hp[t] = h * inv;
            float nVpp = 1.0f + Vpp - 2.f*g*gp[t];
            float nVpv = 0.1f*Vpp + 0.75f*Vpv - 2.f*g*hp[t];
            float nVvv = 0.1f + 0.01f*Vpp + 0.15f*Vpv + 0.5625f*Vvv - 2.f*h*hp[t];
            Vpp = nVpp; Vpv = nVpv; Vvv = nVvv;
        }
    }

    float ua1[T_HOR] = {0,0,0,0,0}, ub1[T_HOR] = {0,0,0,0,0};
    float ua2[T_HOR] = {0,0,0,0,0}, ub2[T_HOR] = {0,0,0,0,0};

    int it_base = 0;
    for (int g = 0; it_base < MAXIT; ++g) {
        const int want = (g == 0) ? g0len : glen;
        const int gl = (MAXIT - it_base < want) ? (MAXIT - it_base) : want;

        // checkpoint controls at group start (== zeros for g=0)
        float ck0[T_HOR], ck1[T_HOR], ck2[T_HOR], ck3[T_HOR];
        #pragma unroll
        for (int t = 0; t < T_HOR; ++t) {
            ck0[t] = ua1[t]; ck1[t] = ub1[t]; ck2[t] = ua2[t]; ck3[t] = ub2[t];
        }

        unsigned mask = 0;
        for (int j = 0; j < gl; ++j) {
            float delta = iter_once(c0, c1, gp, hp, xi.x, xi.y, xi.z, xi.w,
                                    pc_p1, pc_v1, pc_p2, pc_v2,
                                    ua1, ub1, ua2, ub2);
            mask |= (delta > EPSC ? 1u : 0u) << j;
        }

        int m = __syncthreads_or((int)mask);
        if (threadIdx.x == 0 && m) {
            __hip_atomic_fetch_or(&gmask[g], m, __ATOMIC_RELEASE, __HIP_MEMORY_SCOPE_AGENT);
        }
        grid.sync();
        unsigned gm = (unsigned)__hip_atomic_load(&gmask[g], __ATOMIC_ACQUIRE, __HIP_MEMORY_SCOPE_AGENT);

        // first iteration (0-based within group) where ALL elements had delta<=EPS
        unsigned ngm = ~gm;
        int j0 = ngm ? (int)__builtin_ctz(ngm) : 32;   // guard gl==32 full mask
        if (j0 < gl) {
            // stop fired at global iteration it_base+j0+1: restore + replay
            #pragma unroll
            for (int t = 0; t < T_HOR; ++t) {
                ua1[t] = ck0[t]; ub1[t] = ck1[t]; ua2[t] = ck2[t]; ub2[t] = ck3[t];
            }
            for (int j = 0; j <= j0; ++j) {
                iter_once(c0, c1, gp, hp, xi.x, xi.y, xi.z, xi.w,
                          pc_p1, pc_v1, pc_p2, pc_v2,
                          ua1, ub1, ua2, ub2);
            }
            break;
        }
        it_base += gl;
    }

    out[b] = make_float4(ua1[0], ub1[0], ua2[0], ub2[0]);
}

extern "C" void kernel_launch(void* const* d_in, const int* in_sizes, int n_in,
                              void* d_out, int out_size, void* d_ws, size_t ws_size,
                              hipStream_t stream) {
    const float4* x_init = (const float4*)d_in[0];
    const float4* xd     = (const float4*)d_in[1];
    float4* out          = (float4*)d_out;
    int* gmask           = (int*)d_ws;

    const int B = in_sizes[0] / 4;          // 65536
    hipMemsetAsync(d_ws, 0, NFLAGS * sizeof(int), stream);

    int g0len = 32, glen = 4;               // n* estimated in (32,48] from R2 trace
    void* args[] = { (void*)&x_init, (void*)&xd, (void*)&out, (void*)&gmask,
                     (void*)&g0len, (void*)&glen };
    dim3 grid(B / 256), block(256);
    hipLaunchCooperativeKernel((const void*)mpc_iter_kernel, grid, block, args, 0, stream);
}

// Round 9
// 62.476 us; speedup vs baseline: 1.2663x; 1.2663x over previous
//
#include <hip/hip_runtime.h>
#include <hip/hip_cooperative_groups.h>

namespace cg = cooperative_groups;

#define T_HOR 5
#define MAXIT 100
#define KGRP  8
#define NGRP  ((MAXIT + KGRP - 1) / KGRP)   // 13
#define EPSC  0.01f

// One LQR sweep for one batch element (two decoupled 2-state subsystems).
// Returns max |du| over all controls/timesteps. All arrays statically indexed
// inside unrolled T-loops -> fully register-resident.
__device__ __forceinline__ float iter_once(
    const float (&c0)[T_HOR], const float (&c1)[T_HOR],
    const float (&gp)[T_HOR], const float (&hp)[T_HOR],
    float xi0, float xi1, float xi2, float xi3,
    float pc_p1, float pc_v1, float pc_p2, float pc_v2,
    float (&ua1)[T_HOR], float (&ub1)[T_HOR],
    float (&ua2)[T_HOR], float (&ub2)[T_HOR])
{
    // rollout
    float xp1[T_HOR], xv1[T_HOR], xp2[T_HOR], xv2[T_HOR];
    xp1[0] = xi0; xp2[0] = xi1; xv1[0] = xi2; xv2[0] = xi3;
    #pragma unroll
    for (int t = 0; t < T_HOR-1; ++t) {
        xp1[t+1] = xp1[t] + 0.1f*xv1[t];
        xv1[t+1] = 0.75f*xv1[t] + 0.5f*(ua1[t]-ub1[t]);
        xp2[t+1] = xp2[t] + 0.1f*xv2[t];
        xv2[t+1] = 0.75f*xv2[t] + 0.5f*(ua2[t]-ub2[t]);
    }

    // backward affine pass
    float ka1[T_HOR], kb1[T_HOR], ka2[T_HOR], kb2[T_HOR];
    float v1p = 0.f, v1v = 0.f, v2p = 0.f, v2v = 0.f;
    #pragma unroll
    for (int t = T_HOR-1; t >= 0; --t) {
        float qa = 0.01f + 0.1f*ua1[t] + 0.5f*v1v;
        float qb = 0.01f + 0.1f*ub1[t] - 0.5f*v1v;
        ka1[t] = -(c0[t]*qa + c1[t]*qb);
        kb1[t] = -(c1[t]*qa + c0[t]*qb);
        float qxp = (pc_p1 + xp1[t]) + v1p;
        float qxv = (pc_v1 + 0.1f*xv1[t]) + 0.1f*v1p + 0.75f*v1v;
        float dq = qa - qb;
        v1p = qxp - gp[t]*dq;
        v1v = qxv - hp[t]*dq;

        float qa2 = 0.01f + 0.1f*ua2[t] + 0.5f*v2v;
        float qb2 = 0.01f + 0.1f*ub2[t] - 0.5f*v2v;
        ka2[t] = -(c0[t]*qa2 + c1[t]*qb2);
        kb2[t] = -(c1[t]*qa2 + c0[t]*qb2);
        float qxp2 = (pc_p2 + xp2[t]) + v2p;
        float qxv2 = (pc_v2 + 0.1f*xv2[t]) + 0.1f*v2p + 0.75f*v2v;
        float dq2 = qa2 - qb2;
        v2p = qxp2 - gp[t]*dq2;
        v2v = qxv2 - hp[t]*dq2;
    }

    // forward pass with clip
    float delta = 0.f;
    float d1p = 0.f, d1v = 0.f, d2p = 0.f, d2v = 0.f;
    #pragma unroll
    for (int t = 0; t < T_HOR; ++t) {
        float phi1 = gp[t]*d1p + hp[t]*d1v;
        float na = fminf(fmaxf(ua1[t] + (ka1[t] - phi1), 0.f), 1.f);
        float nb = fminf(fmaxf(ub1[t] + (kb1[t] + phi1), 0.f), 1.f);
        float dua = na - ua1[t], dub = nb - ub1[t];
        delta = fmaxf(delta, fmaxf(fabsf(dua), fabsf(dub)));
        float n1p = d1p + 0.1f*d1v;
        float n1v = 0.75f*d1v + 0.5f*(dua - dub);
        d1p = n1p; d1v = n1v;
        ua1[t] = na; ub1[t] = nb;

        float phi2 = gp[t]*d2p + hp[t]*d2v;
        float na2 = fminf(fmaxf(ua2[t] + (ka2[t] - phi2), 0.f), 1.f);
        float nb2 = fminf(fmaxf(ub2[t] + (kb2[t] + phi2), 0.f), 1.f);
        float dua2 = na2 - ua2[t], dub2 = nb2 - ub2[t];
        delta = fmaxf(delta, fmaxf(fabsf(dua2), fabsf(dub2)));
        float n2p = d2p + 0.1f*d2v;
        float n2v = 0.75f*d2v + 0.5f*(dua2 - dub2);
        d2p = n2p; d2v = n2v;
        ua2[t] = na2; ub2[t] = nb2;
    }
    return delta;
}

__global__ __launch_bounds__(256)
void mpc_iter_kernel(const float4* __restrict__ x_init,
                     const float4* __restrict__ xd,
                     float4* __restrict__ out,
                     int* __restrict__ gmask)
{
    cg::grid_group grid = cg::this_grid();
    const int b = blockIdx.x * 256 + threadIdx.x;

    const float4 xi  = x_init[b];   // [p1, p2, v1, v2]
    const float4 xdv = xd[b];
    const float SQ01 = 0.31622776601683794f;
    const float pc_p1 = -xdv.x;
    const float pc_p2 = -xdv.y;
    const float pc_v1 = -SQ01 * xdv.z;
    const float pc_v2 = -SQ01 * xdv.w;

    // Batch-independent Riccati gain schedule (constant-folds at compile time)
    float c0[T_HOR], c1[T_HOR], gp[T_HOR], hp[T_HOR];
    {
        float Vpp = 0.f, Vpv = 0.f, Vvv = 0.f;
        #pragma unroll
        for (int t = T_HOR-1; t >= 0; --t) {
            float s  = 0.25f * Vvv;
            float tw = 0.1f + 2.f*s;
            float dd = 0.1f * tw;
            c0[t] = (0.1f + s) / dd;
            c1[t] = s / dd;
            float g = 0.5f * Vpv;
            float h = 0.05f * Vpv + 0.375f * Vvv;
            float inv = 1.f / tw;
            gp[t] = g * inv;
            hp[t] = h * inv;
            float nVpp = 1.0f + Vpp - 2.f*g*gp[t];
            float nVpv = 0.1f*Vpp + 0.75f*Vpv - 2.f*g*hp[t];
            float nVvv = 0.1f + 0.01f*Vpp + 0.15f*Vpv + 0.5625f*Vvv - 2.f*h*hp[t];
            Vpp = nVpp; Vpv = nVpv; Vvv = nVvv;
        }
    }

    float ua1[T_HOR] = {0,0,0,0,0}, ub1[T_HOR] = {0,0,0,0,0};
    float ua2[T_HOR] = {0,0,0,0,0}, ub2[T_HOR] = {0,0,0,0,0};

    int it_base = 0;
    for (int g = 0; g < NGRP; ++g) {
        // checkpoint controls at group start
        float ck0[T_HOR], ck1[T_HOR], ck2[T_HOR], ck3[T_HOR];
        #pragma unroll
        for (int t = 0; t < T_HOR; ++t) {
            ck0[t] = ua1[t]; ck1[t] = ub1[t]; ck2[t] = ua2[t]; ck3[t] = ub2[t];
        }

        const int gl = (MAXIT - it_base < KGRP) ? (MAXIT - it_base) : KGRP;
        unsigned mask = 0;
        for (int j = 0; j < gl; ++j) {
            float delta = iter_once(c0, c1, gp, hp, xi.x, xi.y, xi.z, xi.w,
                                    pc_p1, pc_v1, pc_p2, pc_v2,
                                    ua1, ub1, ua2, ub2);
            mask |= (delta > EPSC ? 1u : 0u) << j;
        }

        int m = __syncthreads_or((int)mask);
        if (threadIdx.x == 0 && m) {
            __hip_atomic_fetch_or(&gmask[g], m, __ATOMIC_RELEASE, __HIP_MEMORY_SCOPE_AGENT);
        }
        grid.sync();
        int gm = __hip_atomic_load(&gmask[g], __ATOMIC_ACQUIRE, __HIP_MEMORY_SCOPE_AGENT);

        // first iteration (0-based within group) where ALL elements had delta<=EPS
        int j0 = __ffs(~(unsigned)gm) - 1;   // bits >= gl are 0 in gm, so j0<=gl
        if (j0 < gl) {
            // stop fired at global iteration it_base+j0+1: restore + replay
            #pragma unroll
            for (int t = 0; t < T_HOR; ++t) {
                ua1[t] = ck0[t]; ub1[t] = ck1[t]; ua2[t] = ck2[t]; ub2[t] = ck3[t];
            }
            for (int j = 0; j <= j0; ++j) {
                iter_once(c0, c1, gp, hp, xi.x, xi.y, xi.z, xi.w,
                          pc_p1, pc_v1, pc_p2, pc_v2,
                          ua1, ub1, ua2, ub2);
            }
            break;
        }
        it_base += KGRP;
        if (it_base >= MAXIT) break;   // hit iteration cap: output u(MAXIT)
    }

    out[b] = make_float4(ua1[0], ub1[0], ua2[0], ub2[0]);
}

extern "C" void kernel_launch(void* const* d_in, const int* in_sizes, int n_in,
                              void* d_out, int out_size, void* d_ws, size_t ws_size,
                              hipStream_t stream) {
    const float4* x_init = (const float4*)d_in[0];
    const float4* xd     = (const float4*)d_in[1];
    float4* out          = (float4*)d_out;
    int* gmask           = (int*)d_ws;

    const int B = in_sizes[0] / 4;          // 65536
    hipMemsetAsync(d_ws, 0, NGRP * sizeof(int), stream);

    void* args[] = { (void*)&x_init, (void*)&xd, (void*)&out, (void*)&gmask };
    dim3 grid(B / 256), block(256);
    hipLaunchCooperativeKernel((const void*)mpc_iter_kernel, grid, block, args, 0, stream);
}

// Round 10
// 37.035 us; speedup vs baseline: 2.1362x; 1.6869x over previous
//
#include <hip/hip_runtime.h>

#define T_HOR 5
#define MAXIT 100
#define KGRP  8
#define NGRP  ((MAXIT + KGRP - 1) / KGRP)   // 13
#define NBLK  256
#define EPSC  0.01f

// ===== EXACT R9 body — do not modify =====
// One LQR sweep for one batch element (two decoupled 2-state subsystems).
// Returns max |du| over all controls/timesteps.
__device__ __forceinline__ float iter_once(
    const float (&c0)[T_HOR], const float (&c1)[T_HOR],
    const float (&gp)[T_HOR], const float (&hp)[T_HOR],
    float xi0, float xi1, float xi2, float xi3,
    float pc_p1, float pc_v1, float pc_p2, float pc_v2,
    float (&ua1)[T_HOR], float (&ub1)[T_HOR],
    float (&ua2)[T_HOR], float (&ub2)[T_HOR])
{
    // rollout
    float xp1[T_HOR], xv1[T_HOR], xp2[T_HOR], xv2[T_HOR];
    xp1[0] = xi0; xp2[0] = xi1; xv1[0] = xi2; xv2[0] = xi3;
    #pragma unroll
    for (int t = 0; t < T_HOR-1; ++t) {
        xp1[t+1] = xp1[t] + 0.1f*xv1[t];
        xv1[t+1] = 0.75f*xv1[t] + 0.5f*(ua1[t]-ub1[t]);
        xp2[t+1] = xp2[t] + 0.1f*xv2[t];
        xv2[t+1] = 0.75f*xv2[t] + 0.5f*(ua2[t]-ub2[t]);
    }

    // backward affine pass
    float ka1[T_HOR], kb1[T_HOR], ka2[T_HOR], kb2[T_HOR];
    float v1p = 0.f, v1v = 0.f, v2p = 0.f, v2v = 0.f;
    #pragma unroll
    for (int t = T_HOR-1; t >= 0; --t) {
        float qa = 0.01f + 0.1f*ua1[t] + 0.5f*v1v;
        float qb = 0.01f + 0.1f*ub1[t] - 0.5f*v1v;
        ka1[t] = -(c0[t]*qa + c1[t]*qb);
        kb1[t] = -(c1[t]*qa + c0[t]*qb);
        float qxp = (pc_p1 + xp1[t]) + v1p;
        float qxv = (pc_v1 + 0.1f*xv1[t]) + 0.1f*v1p + 0.75f*v1v;
        float dq = qa - qb;
        v1p = qxp - gp[t]*dq;
        v1v = qxv - hp[t]*dq;

        float qa2 = 0.01f + 0.1f*ua2[t] + 0.5f*v2v;
        float qb2 = 0.01f + 0.1f*ub2[t] - 0.5f*v2v;
        ka2[t] = -(c0[t]*qa2 + c1[t]*qb2);
        kb2[t] = -(c1[t]*qa2 + c0[t]*qb2);
        float qxp2 = (pc_p2 + xp2[t]) + v2p;
        float qxv2 = (pc_v2 + 0.1f*xv2[t]) + 0.1f*v2p + 0.75f*v2v;
        float dq2 = qa2 - qb2;
        v2p = qxp2 - gp[t]*dq2;
        v2v = qxv2 - hp[t]*dq2;
    }

    // forward pass with clip
    float delta = 0.f;
    float d1p = 0.f, d1v = 0.f, d2p = 0.f, d2v = 0.f;
    #pragma unroll
    for (int t = 0; t < T_HOR; ++t) {
        float phi1 = gp[t]*d1p + hp[t]*d1v;
        float na = fminf(fmaxf(ua1[t] + (ka1[t] - phi1), 0.f), 1.f);
        float nb = fminf(fmaxf(ub1[t] + (kb1[t] + phi1), 0.f), 1.f);
        float dua = na - ua1[t], dub = nb - ub1[t];
        delta = fmaxf(delta, fmaxf(fabsf(dua), fabsf(dub)));
        float n1p = d1p + 0.1f*d1v;
        float n1v = 0.75f*d1v + 0.5f*(dua - dub);
        d1p = n1p; d1v = n1v;
        ua1[t] = na; ub1[t] = nb;

        float phi2 = gp[t]*d2p + hp[t]*d2v;
        float na2 = fminf(fmaxf(ua2[t] + (ka2[t] - phi2), 0.f), 1.f);
        float nb2 = fminf(fmaxf(ub2[t] + (kb2[t] + phi2), 0.f), 1.f);
        float dua2 = na2 - ua2[t], dub2 = nb2 - ub2[t];
        delta = fmaxf(delta, fmaxf(fabsf(dua2), fabsf(dub2)));
        float n2p = d2p + 0.1f*d2v;
        float n2v = 0.75f*d2v + 0.5f*(dua2 - dub2);
        d2p = n2p; d2v = n2v;
        ua2[t] = na2; ub2[t] = nb2;
    }
    return delta;
}

// R9 structure, but grid.sync() replaced by a one-shot software barrier
// (grid = 256 blocks x 256 threads = 4 waves/CU on 256 CUs -> always fully
// co-resident; counters re-zeroed by the captured memset on every replay).
__global__ __launch_bounds__(256)
void mpc_iter_kernel(const float4* __restrict__ x_init,
                     const float4* __restrict__ xd,
                     float4* __restrict__ out,
                     int* __restrict__ gmask,
                     int* __restrict__ cnt)
{
    const int b = blockIdx.x * 256 + threadIdx.x;

    const float4 xi  = x_init[b];   // [p1, p2, v1, v2]
    const float4 xdv = xd[b];
    const float SQ01 = 0.31622776601683794f;
    const float pc_p1 = -xdv.x;
    const float pc_p2 = -xdv.y;
    const float pc_v1 = -SQ01 * xdv.z;
    const float pc_v2 = -SQ01 * xdv.w;

    // Batch-independent Riccati gain schedule (constant-folds at compile time)
    float c0[T_HOR], c1[T_HOR], gp[T_HOR], hp[T_HOR];
    {
        float Vpp = 0.f, Vpv = 0.f, Vvv = 0.f;
        #pragma unroll
        for (int t = T_HOR-1; t >= 0; --t) {
            float s  = 0.25f * Vvv;
            float tw = 0.1f + 2.f*s;
            float dd = 0.1f * tw;
            c0[t] = (0.1f + s) / dd;
            c1[t] = s / dd;
            float g = 0.5f * Vpv;
            float h = 0.05f * Vpv + 0.375f * Vvv;
            float inv = 1.f / tw;
            gp[t] = g * inv;
            hp[t] = h * inv;
            float nVpp = 1.0f + Vpp - 2.f*g*gp[t];
            float nVpv = 0.1f*Vpp + 0.75f*Vpv - 2.f*g*hp[t];
            float nVvv = 0.1f + 0.01f*Vpp + 0.15f*Vpv + 0.5625f*Vvv - 2.f*h*hp[t];
            Vpp = nVpp; Vpv = nVpv; Vvv = nVvv;
        }
    }

    float ua1[T_HOR] = {0,0,0,0,0}, ub1[T_HOR] = {0,0,0,0,0};
    float ua2[T_HOR] = {0,0,0,0,0}, ub2[T_HOR] = {0,0,0,0,0};

    int it_base = 0;
    for (int g = 0; g < NGRP; ++g) {
        // checkpoint controls at group start
        float ck0[T_HOR], ck1[T_HOR], ck2[T_HOR], ck3[T_HOR];
        #pragma unroll
        for (int t = 0; t < T_HOR; ++t) {
            ck0[t] = ua1[t]; ck1[t] = ub1[t]; ck2[t] = ua2[t]; ck3[t] = ub2[t];
        }

        const int gl = (MAXIT - it_base < KGRP) ? (MAXIT - it_base) : KGRP;
        unsigned mask = 0;
        for (int j = 0; j < gl; ++j) {
            float delta = iter_once(c0, c1, gp, hp, xi.x, xi.y, xi.z, xi.w,
                                    pc_p1, pc_v1, pc_p2, pc_v2,
                                    ua1, ub1, ua2, ub2);
            mask |= (delta > EPSC ? 1u : 0u) << j;
        }

        int m = __syncthreads_or((int)mask);
        // ---- software grid barrier g (one-shot counters, memset-reset per replay)
        if (threadIdx.x == 0) {
            if (m) __hip_atomic_fetch_or(&gmask[g], m, __ATOMIC_RELEASE, __HIP_MEMORY_SCOPE_AGENT);
            __hip_atomic_fetch_add(&cnt[g], 1, __ATOMIC_ACQ_REL, __HIP_MEMORY_SCOPE_AGENT);
            while (__hip_atomic_load(&cnt[g], __ATOMIC_ACQUIRE, __HIP_MEMORY_SCOPE_AGENT) < (int)gridDim.x) {
                __builtin_amdgcn_s_sleep(2);
            }
        }
        __syncthreads();
        int gm = __hip_atomic_load(&gmask[g], __ATOMIC_ACQUIRE, __HIP_MEMORY_SCOPE_AGENT);

        // first iteration (0-based within group) where ALL elements had delta<=EPS
        int j0 = __ffs(~(unsigned)gm) - 1;   // bits >= gl are 0 in gm, so j0<=gl
        if (j0 < gl) {
            // stop fired at global iteration it_base+j0+1: restore + replay
            #pragma unroll
            for (int t = 0; t < T_HOR; ++t) {
                ua1[t] = ck0[t]; ub1[t] = ck1[t]; ua2[t] = ck2[t]; ub2[t] = ck3[t];
            }
            for (int j = 0; j <= j0; ++j) {
                iter_once(c0, c1, gp, hp, xi.x, xi.y, xi.z, xi.w,
                          pc_p1, pc_v1, pc_p2, pc_v2,
                          ua1, ub1, ua2, ub2);
            }
            break;
        }
        it_base += KGRP;
        if (it_base >= MAXIT) break;   // hit iteration cap: output u(MAXIT)
    }

    out[b] = make_float4(ua1[0], ub1[0], ua2[0], ub2[0]);
}

extern "C" void kernel_launch(void* const* d_in, const int* in_sizes, int n_in,
                              void* d_out, int out_size, void* d_ws, size_t ws_size,
                              hipStream_t stream) {
    const float4* x_init = (const float4*)d_in[0];
    const float4* xd     = (const float4*)d_in[1];
    float4* out          = (float4*)d_out;
    int* gmask           = (int*)d_ws;
    int* cnt             = (int*)d_ws + NGRP;

    const int B = in_sizes[0] / 4;          // 65536
    hipMemsetAsync(d_ws, 0, 2 * NGRP * sizeof(int), stream);

    dim3 grid(B / 256), block(256);         // 256 blocks = 4 waves/CU, fully resident
    mpc_iter_kernel<<<grid, block, 0, stream>>>(x_init, xd, out, gmask, cnt);
}

// Round 11
// 35.801 us; speedup vs baseline: 2.2099x; 1.0345x over previous
//
#include <hip/hip_runtime.h>

#define T_HOR 5
#define MAXIT 100
#define KGRP  8
#define NGRP  ((MAXIT + KGRP - 1) / KGRP)   // 13
#define EPSC  0.01f

// One LQR sweep for one batch element (two decoupled 2-state subsystems),
// ROLLOUT FUSED: the state trajectory x[0..T-1] is maintained across
// iterations (x_new[t] = x_old[t] + dx_t, updated in the forward pass),
// so each sweep is backward-pass -> forward-pass only.
__device__ __forceinline__ float iter_once(
    const float (&c0)[T_HOR], const float (&c1)[T_HOR],
    const float (&gp)[T_HOR], const float (&hp)[T_HOR],
    float pc_p1, float pc_v1, float pc_p2, float pc_v2,
    float (&xp1)[T_HOR], float (&xv1)[T_HOR],
    float (&xp2)[T_HOR], float (&xv2)[T_HOR],
    float (&ua1)[T_HOR], float (&ub1)[T_HOR],
    float (&ua2)[T_HOR], float (&ub2)[T_HOR])
{
    // backward affine pass (x trajectory is current: maintained by fwd pass)
    float ka1[T_HOR], kb1[T_HOR], ka2[T_HOR], kb2[T_HOR];
    float v1p = 0.f, v1v = 0.f, v2p = 0.f, v2v = 0.f;
    #pragma unroll
    for (int t = T_HOR-1; t >= 0; --t) {
        float qa = 0.01f + 0.1f*ua1[t] + 0.5f*v1v;
        float qb = 0.01f + 0.1f*ub1[t] - 0.5f*v1v;
        ka1[t] = -(c0[t]*qa + c1[t]*qb);
        kb1[t] = -(c1[t]*qa + c0[t]*qb);
        float qxp = (pc_p1 + xp1[t]) + v1p;
        float qxv = (pc_v1 + 0.1f*xv1[t]) + 0.1f*v1p + 0.75f*v1v;
        float dq = qa - qb;
        v1p = qxp - gp[t]*dq;
        v1v = qxv - hp[t]*dq;

        float qa2 = 0.01f + 0.1f*ua2[t] + 0.5f*v2v;
        float qb2 = 0.01f + 0.1f*ub2[t] - 0.5f*v2v;
        ka2[t] = -(c0[t]*qa2 + c1[t]*qb2);
        kb2[t] = -(c1[t]*qa2 + c0[t]*qb2);
        float qxp2 = (pc_p2 + xp2[t]) + v2p;
        float qxv2 = (pc_v2 + 0.1f*xv2[t]) + 0.1f*v2p + 0.75f*v2v;
        float dq2 = qa2 - qb2;
        v2p = qxp2 - gp[t]*dq2;
        v2v = qxv2 - hp[t]*dq2;
    }

    // forward pass with clip: update u AND x in place (x[t] += dx_t)
    float delta = 0.f;
    float d1p = 0.f, d1v = 0.f, d2p = 0.f, d2v = 0.f;
    #pragma unroll
    for (int t = 0; t < T_HOR; ++t) {
        float phi1 = gp[t]*d1p + hp[t]*d1v;
        float na = fminf(fmaxf(ua1[t] + (ka1[t] - phi1), 0.f), 1.f);
        float nb = fminf(fmaxf(ub1[t] + (kb1[t] + phi1), 0.f), 1.f);
        float dua = na - ua1[t], dub = nb - ub1[t];
        delta = fmaxf(delta, fmaxf(fabsf(dua), fabsf(dub)));
        xp1[t] += d1p; xv1[t] += d1v;          // x_new[t] = x_old[t] + dx_t
        float n1p = d1p + 0.1f*d1v;
        float n1v = 0.75f*d1v + 0.5f*(dua - dub);
        d1p = n1p; d1v = n1v;
        ua1[t] = na; ub1[t] = nb;

        float phi2 = gp[t]*d2p + hp[t]*d2v;
        float na2 = fminf(fmaxf(ua2[t] + (ka2[t] - phi2), 0.f), 1.f);
        float nb2 = fminf(fmaxf(ub2[t] + (kb2[t] + phi2), 0.f), 1.f);
        float dua2 = na2 - ua2[t], dub2 = nb2 - ub2[t];
        delta = fmaxf(delta, fmaxf(fabsf(dua2), fabsf(dub2)));
        xp2[t] += d2p; xv2[t] += d2v;
        float n2p = d2p + 0.1f*d2v;
        float n2v = 0.75f*d2v + 0.5f*(dua2 - dub2);
        d2p = n2p; d2v = n2v;
        ua2[t] = na2; ub2[t] = nb2;
    }
    return delta;
}

// R10 structure (software grid barrier, KGRP=8 groups, checkpoint+replay);
// checkpoint now covers u AND x (both restored before replay).
__global__ __launch_bounds__(256)
void mpc_iter_kernel(const float4* __restrict__ x_init,
                     const float4* __restrict__ xd,
                     float4* __restrict__ out,
                     int* __restrict__ gmask,
                     int* __restrict__ cnt)
{
    const int b = blockIdx.x * 256 + threadIdx.x;

    const float4 xi  = x_init[b];   // [p1, p2, v1, v2]
    const float4 xdv = xd[b];
    const float SQ01 = 0.31622776601683794f;
    const float pc_p1 = -xdv.x;
    const float pc_p2 = -xdv.y;
    const float pc_v1 = -SQ01 * xdv.z;
    const float pc_v2 = -SQ01 * xdv.w;

    // Batch-independent Riccati gain schedule (constant-folds at compile time)
    float c0[T_HOR], c1[T_HOR], gp[T_HOR], hp[T_HOR];
    {
        float Vpp = 0.f, Vpv = 0.f, Vvv = 0.f;
        #pragma unroll
        for (int t = T_HOR-1; t >= 0; --t) {
            float s  = 0.25f * Vvv;
            float tw = 0.1f + 2.f*s;
            float dd = 0.1f * tw;
            c0[t] = (0.1f + s) / dd;
            c1[t] = s / dd;
            float g = 0.5f * Vpv;
            float h = 0.05f * Vpv + 0.375f * Vvv;
            float inv = 1.f / tw;
            gp[t] = g * inv;
            hp[t] = h * inv;
            float nVpp = 1.0f + Vpp - 2.f*g*gp[t];
            float nVpv = 0.1f*Vpp + 0.75f*Vpv - 2.f*g*hp[t];
            float nVvv = 0.1f + 0.01f*Vpp + 0.15f*Vpv + 0.5625f*Vvv - 2.f*h*hp[t];
            Vpp = nVpp; Vpv = nVpv; Vvv = nVvv;
        }
    }

    // u = 0; x = rollout(x_init, u=0)  (the only explicit rollout, once)
    float ua1[T_HOR] = {0,0,0,0,0}, ub1[T_HOR] = {0,0,0,0,0};
    float ua2[T_HOR] = {0,0,0,0,0}, ub2[T_HOR] = {0,0,0,0,0};
    float xp1[T_HOR], xv1[T_HOR], xp2[T_HOR], xv2[T_HOR];
    xp1[0] = xi.x; xp2[0] = xi.y; xv1[0] = xi.z; xv2[0] = xi.w;
    #pragma unroll
    for (int t = 0; t < T_HOR-1; ++t) {
        xp1[t+1] = xp1[t] + 0.1f*xv1[t];
        xv1[t+1] = 0.75f*xv1[t];
        xp2[t+1] = xp2[t] + 0.1f*xv2[t];
        xv2[t+1] = 0.75f*xv2[t];
    }

    int it_base = 0;
    for (int g = 0; g < NGRP; ++g) {
        // checkpoint controls AND state trajectory at group start
        float cka1[T_HOR], ckb1[T_HOR], cka2[T_HOR], ckb2[T_HOR];
        float ckp1[T_HOR], ckv1[T_HOR], ckp2[T_HOR], ckv2[T_HOR];
        #pragma unroll
        for (int t = 0; t < T_HOR; ++t) {
            cka1[t] = ua1[t]; ckb1[t] = ub1[t]; cka2[t] = ua2[t]; ckb2[t] = ub2[t];
            ckp1[t] = xp1[t]; ckv1[t] = xv1[t]; ckp2[t] = xp2[t]; ckv2[t] = xv2[t];
        }

        const int gl = (MAXIT - it_base < KGRP) ? (MAXIT - it_base) : KGRP;
        unsigned mask = 0;
        for (int j = 0; j < gl; ++j) {
            float delta = iter_once(c0, c1, gp, hp,
                                    pc_p1, pc_v1, pc_p2, pc_v2,
                                    xp1, xv1, xp2, xv2,
                                    ua1, ub1, ua2, ub2);
            mask |= (delta > EPSC ? 1u : 0u) << j;
        }

        int m = __syncthreads_or((int)mask);
        // ---- software grid barrier g (one-shot counters, memset-reset per replay)
        if (threadIdx.x == 0) {
            if (m) __hip_atomic_fetch_or(&gmask[g], m, __ATOMIC_RELEASE, __HIP_MEMORY_SCOPE_AGENT);
            __hip_atomic_fetch_add(&cnt[g], 1, __ATOMIC_ACQ_REL, __HIP_MEMORY_SCOPE_AGENT);
            while (__hip_atomic_load(&cnt[g], __ATOMIC_ACQUIRE, __HIP_MEMORY_SCOPE_AGENT) < (int)gridDim.x) {
                __builtin_amdgcn_s_sleep(2);
            }
        }
        __syncthreads();
        int gm = __hip_atomic_load(&gmask[g], __ATOMIC_ACQUIRE, __HIP_MEMORY_SCOPE_AGENT);

        // first iteration (0-based within group) where ALL elements had delta<=EPS
        int j0 = __ffs(~(unsigned)gm) - 1;   // bits >= gl are 0 in gm, so j0<=gl
        if (j0 < gl) {
            // stop fired at global iteration it_base+j0+1: restore u,x + replay
            #pragma unroll
            for (int t = 0; t < T_HOR; ++t) {
                ua1[t] = cka1[t]; ub1[t] = ckb1[t]; ua2[t] = cka2[t]; ub2[t] = ckb2[t];
                xp1[t] = ckp1[t]; xv1[t] = ckv1[t]; xp2[t] = ckp2[t]; xv2[t] = ckv2[t];
            }
            for (int j = 0; j <= j0; ++j) {
                iter_once(c0, c1, gp, hp,
                          pc_p1, pc_v1, pc_p2, pc_v2,
                          xp1, xv1, xp2, xv2,
                          ua1, ub1, ua2, ub2);
            }
            break;
        }
        it_base += KGRP;
        if (it_base >= MAXIT) break;   // hit iteration cap: output u(MAXIT)
    }

    out[b] = make_float4(ua1[0], ub1[0], ua2[0], ub2[0]);
}

extern "C" void kernel_launch(void* const* d_in, const int* in_sizes, int n_in,
                              void* d_out, int out_size, void* d_ws, size_t ws_size,
                              hipStream_t stream) {
    const float4* x_init = (const float4*)d_in[0];
    const float4* xd     = (const float4*)d_in[1];
    float4* out          = (float4*)d_out;
    int* gmask           = (int*)d_ws;
    int* cnt             = (int*)d_ws + NGRP;

    const int B = in_sizes[0] / 4;          // 65536
    hipMemsetAsync(d_ws, 0, 2 * NGRP * sizeof(int), stream);

    dim3 grid(B / 256), block(256);         // 256 blocks = 4 waves/CU, fully resident
    mpc_iter_kernel<<<grid, block, 0, stream>>>(x_init, xd, out, gmask, cnt);
}